// Round 1
// baseline (1290.288 us; speedup 1.0000x reference)
//
#include <hip/hip_runtime.h>
#include <hip/hip_bf16.h>
#include <math.h>

// FEAf lowpass: b=4, t=2048, c=64, mw=64, modes=16, SCALE=1/4096.
// Stage A: 16-mode DFT over t (radix-4 folded), float2 lanes, LDS twiddles.
//          v2: CH=16 chunks (ws permitting) + explicit load prefetch for MLP.
// reduceP: sum chunk partials.
// Stage B: per (b,h) complex 16x16 attention w/ complex tanh.
// Stage C: 16-mode inverse (radix-2 Hermitian over t), TT=16 for occupancy.

#define T_DIM 2048
#define DH 4096           // c*mw
#define DH2 2048          // float2 view
#define TT 16             // stageC t-tile (over t in [0,1024)) -> 64 tiles

// ---------------- twiddle tables ----------------
// WA[t'][2m]=cos(2pi m t'/2048), WA[t'][2m+1]=sin(...)           (t' in [0,512))
// Bt2[t][2m]=coef_m cos(2pi m t/2048), [2m+1]=-coef_m sin(...)   (t in [0,1024))
__global__ void init_tables(float* __restrict__ WA, float* __restrict__ Bt2) {
    int i = blockIdx.x * 256 + threadIdx.x;
    const float TWO_PI = 6.2831853071795864769f;
    if (i < 512 * 32) {
        int t = i >> 5, r = i & 31, m = r >> 1;
        int ph = (m * t) & 2047;
        float ang = TWO_PI * (float)ph * (1.0f / 2048.0f);
        WA[i] = (r & 1) ? sinf(ang) : cosf(ang);
    }
    int i2 = i - 512 * 32;
    if (i2 >= 0 && i2 < 1024 * 32) {
        int t = i2 >> 5, r = i2 & 31, m = r >> 1;
        int ph = (m * t) & 2047;
        float ang = TWO_PI * (float)ph * (1.0f / 2048.0f);
        const float S2 = 1.0f / (4096.0f * 2048.0f);
        float coef = (m == 0 ? 1.0f : 2.0f) * S2;
        float val;
        if (!(r & 1)) val = coef * cosf(ang);
        else          val = (m == 0) ? 0.0f : -coef * sinf(ang);
        Bt2[i2] = val;
    }
}

// ---------------- stage A ----------------
// P[tz][chunk][j][dh]; j: 0..15 Re, 16..31 Im. tz = tensor*4 + b.
#define STAGEA_BODY(TL) do {                                                   \
    float2 u0 = make_float2(x0.x + x2.x, x0.y + x2.y);                         \
    float2 u1 = make_float2(x1.x + x3.x, x1.y + x3.y);                         \
    float2 d0 = make_float2(x0.x - x2.x, x0.y - x2.y);                         \
    float2 d1 = make_float2(x1.x - x3.x, x1.y - x3.y);                         \
    float2 e  = make_float2(u0.x + u1.x, u0.y + u1.y);                         \
    float2 f  = make_float2(u0.x - u1.x, u0.y - u1.y);                         \
    const float* ww = &w[(TL) * 32];                                           \
    _Pragma("unroll")                                                          \
    for (int m = 0; m < 16; m++) {                                             \
        float cm = ww[2 * m], sm = ww[2 * m + 1];                              \
        if ((m & 3) == 0) {                                                    \
            accR[m].x = fmaf(cm, e.x, accR[m].x);                              \
            accR[m].y = fmaf(cm, e.y, accR[m].y);                              \
            accI[m].x = fmaf(-sm, e.x, accI[m].x);                             \
            accI[m].y = fmaf(-sm, e.y, accI[m].y);                             \
        } else if ((m & 3) == 2) {                                             \
            accR[m].x = fmaf(cm, f.x, accR[m].x);                              \
            accR[m].y = fmaf(cm, f.y, accR[m].y);                              \
            accI[m].x = fmaf(-sm, f.x, accI[m].x);                             \
            accI[m].y = fmaf(-sm, f.y, accI[m].y);                             \
        } else if ((m & 3) == 1) {                                             \
            accR[m].x = fmaf(cm, d0.x, fmaf(-sm, d1.x, accR[m].x));            \
            accR[m].y = fmaf(cm, d0.y, fmaf(-sm, d1.y, accR[m].y));            \
            accI[m].x = fmaf(-sm, d0.x, fmaf(-cm, d1.x, accI[m].x));           \
            accI[m].y = fmaf(-sm, d0.y, fmaf(-cm, d1.y, accI[m].y));           \
        } else {                                                               \
            accR[m].x = fmaf(cm, d0.x, fmaf(sm, d1.x, accR[m].x));             \
            accR[m].y = fmaf(cm, d0.y, fmaf(sm, d1.y, accR[m].y));             \
            accI[m].x = fmaf(-sm, d0.x, fmaf(cm, d1.x, accI[m].x));            \
            accI[m].y = fmaf(-sm, d0.y, fmaf(cm, d1.y, accI[m].y));            \
        }                                                                      \
    }                                                                          \
} while (0)

template <int CH_>
__global__ __launch_bounds__(256, 5) void stageA(
        const float* __restrict__ q, const float* __restrict__ k,
        const float* __restrict__ v, const float* __restrict__ WA,
        float* __restrict__ P) {
    constexpr int TPCH_ = 512 / CH_;           // t' per chunk
    __shared__ float w[TPCH_ * 32];
    int tid = threadIdx.x;
    int c   = blockIdx.y;
    int tz  = blockIdx.z;
    int tensor = tz >> 2, b = tz & 3;

    #pragma unroll
    for (int it = 0; it < TPCH_ * 32 / 256; it++)
        w[it * 256 + tid] = WA[c * (TPCH_ * 32) + it * 256 + tid];
    __syncthreads();

    int dh2 = blockIdx.x * 256 + tid;    // float2 index into DH
    const float* srcf = (tensor == 0 ? q : tensor == 1 ? k : v)
                        + (size_t)b * T_DIM * DH;
    const float2* p0 = (const float2*)srcf + (size_t)(c * TPCH_) * DH2 + dh2;

    float2 accR[16], accI[16];
    #pragma unroll
    for (int m = 0; m < 16; m++) {
        accR[m] = make_float2(0.f, 0.f);
        accI[m] = make_float2(0.f, 0.f);
    }

    // software pipeline: keep next iteration's 4 loads in flight during FMAs
    float2 x0 = p0[0];
    float2 x1 = p0[(size_t)512 * DH2];
    float2 x2 = p0[(size_t)1024 * DH2];
    float2 x3 = p0[(size_t)1536 * DH2];

    #pragma unroll 2
    for (int tl = 0; tl < TPCH_ - 1; tl++) {
        const float2* pn = p0 + (size_t)(tl + 1) * DH2;
        float2 n0 = pn[0];
        float2 n1 = pn[(size_t)512 * DH2];
        float2 n2 = pn[(size_t)1024 * DH2];
        float2 n3 = pn[(size_t)1536 * DH2];
        STAGEA_BODY(tl);
        x0 = n0; x1 = n1; x2 = n2; x3 = n3;
    }
    STAGEA_BODY(TPCH_ - 1);

    float2* pp = (float2*)P + (((size_t)tz * CH_ + c) * 32) * DH2 + dh2;
    #pragma unroll
    for (int m = 0; m < 16; m++) {
        pp[(size_t)m * DH2]        = accR[m];
        pp[(size_t)(16 + m) * DH2] = accI[m];
    }
}

// ---------------- reduce chunk partials: Y[tz][j][dh] ----------------
template <int CH_>
__global__ __launch_bounds__(256) void reduceP(const float4* __restrict__ P,
                                               float4* __restrict__ Y) {
    size_t i   = (size_t)blockIdx.x * 256 + threadIdx.x;  // 12*32*1024
    size_t tzj = i >> 10;
    size_t dh4 = i & 1023;
    size_t tz  = tzj >> 5;
    size_t j   = tzj & 31;
    const float4* p = P + ((tz * CH_) * 32 + j) * 1024 + dh4;
    float4 s = make_float4(0.f, 0.f, 0.f, 0.f);
    #pragma unroll
    for (int cc = 0; cc < CH_; cc++) {
        float4 t = p[(size_t)cc * 32 * 1024];
        s.x += t.x; s.y += t.y; s.z += t.z; s.w += t.w;
    }
    Y[i] = s;
}

// ---------------- stage B: complex mode-space attention ----------------
// G[b][j][dh], j: 0..15 Re(qkv), 16..31 Im(qkv)
__global__ __launch_bounds__(256) void stageB(const float* __restrict__ Y,
                                              float* __restrict__ G) {
    __shared__ float qf[64 * 33];
    __shared__ float kf[64 * 33];
    __shared__ float vf[64 * 33];
    __shared__ float qkr[16 * 17];
    __shared__ float qki[16 * 17];

    int tid = threadIdx.x;
    int bh  = blockIdx.x;
    int b   = bh >> 6;
    int h   = bh & 63;

    #pragma unroll
    for (int tensor = 0; tensor < 3; tensor++) {
        float* dst = (tensor == 0 ? qf : tensor == 1 ? kf : vf);
        const float* yp = Y + ((size_t)(tensor * 4 + b) * 32) * DH + h;
        #pragma unroll
        for (int it = 0; it < 8; it++) {
            int p = it * 256 + tid;
            int d = p & 63, j = p >> 6;
            dst[d * 33 + j] = yp[(size_t)j * DH + d * 64];
        }
    }
    __syncthreads();

    int x = tid >> 4, y = tid & 15;
    float ar = 0.f, ai = 0.f;
    #pragma unroll 4
    for (int d = 0; d < 64; d++) {
        float qr = qf[d * 33 + x],      qi = qf[d * 33 + 16 + x];
        float kr = kf[d * 33 + y],      ki = kf[d * 33 + 16 + y];
        ar += qr * kr - qi * ki;
        ai += qr * ki + qi * kr;
    }
    float re, im;
    float a2 = 2.f * ar, b2 = 2.f * ai;
    if (fabsf(a2) < 80.f) {
        float den = coshf(a2) + cosf(b2);
        re = sinhf(a2) / den;
        im = sinf(b2) / den;
    } else {
        re = copysignf(1.f, ar);
        im = 0.f;
    }
    qkr[x * 17 + y] = re;
    qki[x * 17 + y] = im;
    __syncthreads();

    int xx = tid & 15, db = tid >> 4;
    #pragma unroll
    for (int i = 0; i < 4; i++) {
        int d = db + i * 16;
        float cr = 0.f, ci = 0.f;
        #pragma unroll
        for (int yy = 0; yy < 16; yy++) {
            float tr = qkr[xx * 17 + yy], ti = qki[xx * 17 + yy];
            float vr = vf[d * 33 + yy],   vi = vf[d * 33 + 16 + yy];
            cr += tr * vr - ti * vi;
            ci += tr * vi + ti * vr;
        }
        G[((size_t)b * 32 + xx) * DH + d * 64 + h]      = cr;
        G[((size_t)b * 32 + 16 + xx) * DH + d * 64 + h] = ci;
    }
}

// ---------------- stage C: inverse, radix-2 Hermitian over t ----------------
__global__ __launch_bounds__(256, 6) void stageC(const float* __restrict__ G,
                                                 const float* __restrict__ Bt2,
                                                 float* __restrict__ out) {
    __shared__ float w[TT * 32];   // 2 KB basis tile
    int tid = threadIdx.x;
    int c   = blockIdx.y;          // t-tile over [0,1024), 64 tiles
    int b   = blockIdx.z;

    #pragma unroll
    for (int it = 0; it < TT * 32 / 256; it++)
        w[it * 256 + tid] = Bt2[c * (TT * 32) + it * 256 + tid];
    __syncthreads();

    int dh2 = blockIdx.x * 256 + tid;
    float2 gr[16], gi[16];
    const float2* gp = (const float2*)G + (size_t)b * 32 * DH2 + dh2;
    #pragma unroll
    for (int m = 0; m < 16; m++) {
        gr[m] = gp[(size_t)m * DH2];
        gi[m] = gp[(size_t)(16 + m) * DH2];
    }

    float2* o0 = (float2*)out + ((size_t)b * T_DIM + (size_t)c * TT) * DH2 + dh2;
    #pragma unroll 2
    for (int tl = 0; tl < TT; tl++) {
        const float* ww = &w[tl * 32];
        float2 E = make_float2(0.f, 0.f), O = make_float2(0.f, 0.f);
        #pragma unroll
        for (int m = 0; m < 16; m += 2) {
            E.x = fmaf(ww[2 * m],     gr[m].x, E.x);
            E.x = fmaf(ww[2 * m + 1], gi[m].x, E.x);
            E.y = fmaf(ww[2 * m],     gr[m].y, E.y);
            E.y = fmaf(ww[2 * m + 1], gi[m].y, E.y);
        }
        #pragma unroll
        for (int m = 1; m < 16; m += 2) {
            O.x = fmaf(ww[2 * m],     gr[m].x, O.x);
            O.x = fmaf(ww[2 * m + 1], gi[m].x, O.x);
            O.y = fmaf(ww[2 * m],     gr[m].y, O.y);
            O.y = fmaf(ww[2 * m + 1], gi[m].y, O.y);
        }
        o0[(size_t)tl * DH2] = make_float2(E.x + O.x, E.y + O.y);
        o0[(size_t)(tl + 1024) * DH2] = make_float2(E.x - O.x, E.y - O.y);
    }
}

extern "C" void kernel_launch(void* const* d_in, const int* in_sizes, int n_in,
                              void* d_out, int out_size, void* d_ws, size_t ws_size,
                              hipStream_t stream) {
    const float* q = (const float*)d_in[0];
    const float* k = (const float*)d_in[1];
    const float* v = (const float*)d_in[2];
    float* out = (float*)d_out;

    char* ws = (char*)d_ws;
    float* WA  = (float*)ws;                         //    65536 B
    float* Bt2 = (float*)(ws + 65536);               //   131072 B
    const size_t base = 65536 + 131072;

    const size_t psz16 = (size_t)12 * 16 * 32 * DH * 4;   // 100663296 B
    const size_t psz8  = (size_t)12 *  8 * 32 * DH * 4;   //  50331648 B
    const size_t ysz   = 6291456, gsz = 2097152;
    const bool big = ws_size >= base + psz16 + ysz + gsz; // 109.2 MB

    size_t psz = big ? psz16 : psz8;
    float* P = (float*)(ws + base);
    float* Y = (float*)(ws + base + psz);
    float* G = (float*)(ws + base + psz + ysz);

    init_tables<<<192, 256, 0, stream>>>(WA, Bt2);
    if (big) {
        stageA<16><<<dim3(8, 16, 12), 256, 0, stream>>>(q, k, v, WA, P);
        reduceP<16><<<1536, 256, 0, stream>>>((const float4*)P, (float4*)Y);
    } else {
        stageA<8><<<dim3(8, 8, 12), 256, 0, stream>>>(q, k, v, WA, P);
        reduceP<8><<<1536, 256, 0, stream>>>((const float4*)P, (float4*)Y);
    }
    stageB<<<256, 256, 0, stream>>>(Y, G);
    stageC<<<dim3(8, 64, 4), 256, 0, stream>>>(G, Bt2, out);
}

// Round 2
// 466.913 us; speedup vs baseline: 2.7634x; 2.7634x over previous
//
#include <hip/hip_runtime.h>
#include <hip/hip_bf16.h>
#include <math.h>

// FEAf lowpass: b=4, t=2048, c=64, mw=64, modes=16, SCALE=1/4096.
// Stage A: 16-mode DFT over t (radix-4 folded), float2 lanes, LDS twiddles.
//          CH=16 chunks (ws permitting) + explicit load prefetch for MLP.
//          NOTE: no min-waves launch_bounds — a register cap here spills the
//          64-float accumulator array to scratch (round-1: 1.2 GB WRITE_SIZE).
// reduceP: sum chunk partials.
// Stage B: per (b,h) complex 16x16 attention w/ complex tanh.
// Stage C: 16-mode inverse (radix-2 Hermitian over t), TT=16 for occupancy.

#define T_DIM 2048
#define DH 4096           // c*mw
#define DH2 2048          // float2 view
#define TT 16             // stageC t-tile (over t in [0,1024)) -> 64 tiles

// ---------------- twiddle tables ----------------
// WA[t'][2m]=cos(2pi m t'/2048), WA[t'][2m+1]=sin(...)           (t' in [0,512))
// Bt2[t][2m]=coef_m cos(2pi m t/2048), [2m+1]=-coef_m sin(...)   (t in [0,1024))
__global__ void init_tables(float* __restrict__ WA, float* __restrict__ Bt2) {
    int i = blockIdx.x * 256 + threadIdx.x;
    const float TWO_PI = 6.2831853071795864769f;
    if (i < 512 * 32) {
        int t = i >> 5, r = i & 31, m = r >> 1;
        int ph = (m * t) & 2047;
        float ang = TWO_PI * (float)ph * (1.0f / 2048.0f);
        WA[i] = (r & 1) ? sinf(ang) : cosf(ang);
    }
    int i2 = i - 512 * 32;
    if (i2 >= 0 && i2 < 1024 * 32) {
        int t = i2 >> 5, r = i2 & 31, m = r >> 1;
        int ph = (m * t) & 2047;
        float ang = TWO_PI * (float)ph * (1.0f / 2048.0f);
        const float S2 = 1.0f / (4096.0f * 2048.0f);
        float coef = (m == 0 ? 1.0f : 2.0f) * S2;
        float val;
        if (!(r & 1)) val = coef * cosf(ang);
        else          val = (m == 0) ? 0.0f : -coef * sinf(ang);
        Bt2[i2] = val;
    }
}

// ---------------- stage A ----------------
// P[tz][chunk][j][dh]; j: 0..15 Re, 16..31 Im. tz = tensor*4 + b.
#define STAGEA_BODY(TL) do {                                                   \
    float2 u0 = make_float2(x0.x + x2.x, x0.y + x2.y);                         \
    float2 u1 = make_float2(x1.x + x3.x, x1.y + x3.y);                         \
    float2 d0 = make_float2(x0.x - x2.x, x0.y - x2.y);                         \
    float2 d1 = make_float2(x1.x - x3.x, x1.y - x3.y);                         \
    float2 e  = make_float2(u0.x + u1.x, u0.y + u1.y);                         \
    float2 f  = make_float2(u0.x - u1.x, u0.y - u1.y);                         \
    const float* ww = &w[(TL) * 32];                                           \
    _Pragma("unroll")                                                          \
    for (int m = 0; m < 16; m++) {                                             \
        float cm = ww[2 * m], sm = ww[2 * m + 1];                              \
        if ((m & 3) == 0) {                                                    \
            accR[m].x = fmaf(cm, e.x, accR[m].x);                              \
            accR[m].y = fmaf(cm, e.y, accR[m].y);                              \
            accI[m].x = fmaf(-sm, e.x, accI[m].x);                             \
            accI[m].y = fmaf(-sm, e.y, accI[m].y);                             \
        } else if ((m & 3) == 2) {                                             \
            accR[m].x = fmaf(cm, f.x, accR[m].x);                              \
            accR[m].y = fmaf(cm, f.y, accR[m].y);                              \
            accI[m].x = fmaf(-sm, f.x, accI[m].x);                             \
            accI[m].y = fmaf(-sm, f.y, accI[m].y);                             \
        } else if ((m & 3) == 1) {                                             \
            accR[m].x = fmaf(cm, d0.x, fmaf(-sm, d1.x, accR[m].x));            \
            accR[m].y = fmaf(cm, d0.y, fmaf(-sm, d1.y, accR[m].y));            \
            accI[m].x = fmaf(-sm, d0.x, fmaf(-cm, d1.x, accI[m].x));           \
            accI[m].y = fmaf(-sm, d0.y, fmaf(-cm, d1.y, accI[m].y));           \
        } else {                                                               \
            accR[m].x = fmaf(cm, d0.x, fmaf(sm, d1.x, accR[m].x));             \
            accR[m].y = fmaf(cm, d0.y, fmaf(sm, d1.y, accR[m].y));             \
            accI[m].x = fmaf(-sm, d0.x, fmaf(cm, d1.x, accI[m].x));            \
            accI[m].y = fmaf(-sm, d0.y, fmaf(cm, d1.y, accI[m].y));            \
        }                                                                      \
    }                                                                          \
} while (0)

template <int CH_>
__global__ __launch_bounds__(256) void stageA(
        const float* __restrict__ q, const float* __restrict__ k,
        const float* __restrict__ v, const float* __restrict__ WA,
        float* __restrict__ P) {
    constexpr int TPCH_ = 512 / CH_;           // t' per chunk
    __shared__ float w[TPCH_ * 32];
    int tid = threadIdx.x;
    int c   = blockIdx.y;
    int tz  = blockIdx.z;
    int tensor = tz >> 2, b = tz & 3;

    #pragma unroll
    for (int it = 0; it < TPCH_ * 32 / 256; it++)
        w[it * 256 + tid] = WA[c * (TPCH_ * 32) + it * 256 + tid];
    __syncthreads();

    int dh2 = blockIdx.x * 256 + tid;    // float2 index into DH
    const float* srcf = (tensor == 0 ? q : tensor == 1 ? k : v)
                        + (size_t)b * T_DIM * DH;
    const float2* p0 = (const float2*)srcf + (size_t)(c * TPCH_) * DH2 + dh2;

    float2 accR[16], accI[16];
    #pragma unroll
    for (int m = 0; m < 16; m++) {
        accR[m] = make_float2(0.f, 0.f);
        accI[m] = make_float2(0.f, 0.f);
    }

    // software pipeline: keep next iteration's 4 loads in flight during FMAs
    float2 x0 = p0[0];
    float2 x1 = p0[(size_t)512 * DH2];
    float2 x2 = p0[(size_t)1024 * DH2];
    float2 x3 = p0[(size_t)1536 * DH2];

    #pragma unroll 2
    for (int tl = 0; tl < TPCH_ - 1; tl++) {
        const float2* pn = p0 + (size_t)(tl + 1) * DH2;
        float2 n0 = pn[0];
        float2 n1 = pn[(size_t)512 * DH2];
        float2 n2 = pn[(size_t)1024 * DH2];
        float2 n3 = pn[(size_t)1536 * DH2];
        STAGEA_BODY(tl);
        x0 = n0; x1 = n1; x2 = n2; x3 = n3;
    }
    STAGEA_BODY(TPCH_ - 1);

    float2* pp = (float2*)P + (((size_t)tz * CH_ + c) * 32) * DH2 + dh2;
    #pragma unroll
    for (int m = 0; m < 16; m++) {
        pp[(size_t)m * DH2]        = accR[m];
        pp[(size_t)(16 + m) * DH2] = accI[m];
    }
}

// ---------------- reduce chunk partials: Y[tz][j][dh] ----------------
template <int CH_>
__global__ __launch_bounds__(256) void reduceP(const float4* __restrict__ P,
                                               float4* __restrict__ Y) {
    size_t i   = (size_t)blockIdx.x * 256 + threadIdx.x;  // 12*32*1024
    size_t tzj = i >> 10;
    size_t dh4 = i & 1023;
    size_t tz  = tzj >> 5;
    size_t j   = tzj & 31;
    const float4* p = P + ((tz * CH_) * 32 + j) * 1024 + dh4;
    float4 s = make_float4(0.f, 0.f, 0.f, 0.f);
    #pragma unroll
    for (int cc = 0; cc < CH_; cc++) {
        float4 t = p[(size_t)cc * 32 * 1024];
        s.x += t.x; s.y += t.y; s.z += t.z; s.w += t.w;
    }
    Y[i] = s;
}

// ---------------- stage B: complex mode-space attention ----------------
// G[b][j][dh], j: 0..15 Re(qkv), 16..31 Im(qkv)
__global__ __launch_bounds__(256) void stageB(const float* __restrict__ Y,
                                              float* __restrict__ G) {
    __shared__ float qf[64 * 33];
    __shared__ float kf[64 * 33];
    __shared__ float vf[64 * 33];
    __shared__ float qkr[16 * 17];
    __shared__ float qki[16 * 17];

    int tid = threadIdx.x;
    int bh  = blockIdx.x;
    int b   = bh >> 6;
    int h   = bh & 63;

    #pragma unroll
    for (int tensor = 0; tensor < 3; tensor++) {
        float* dst = (tensor == 0 ? qf : tensor == 1 ? kf : vf);
        const float* yp = Y + ((size_t)(tensor * 4 + b) * 32) * DH + h;
        #pragma unroll
        for (int it = 0; it < 8; it++) {
            int p = it * 256 + tid;
            int d = p & 63, j = p >> 6;
            dst[d * 33 + j] = yp[(size_t)j * DH + d * 64];
        }
    }
    __syncthreads();

    int x = tid >> 4, y = tid & 15;
    float ar = 0.f, ai = 0.f;
    #pragma unroll 4
    for (int d = 0; d < 64; d++) {
        float qr = qf[d * 33 + x],      qi = qf[d * 33 + 16 + x];
        float kr = kf[d * 33 + y],      ki = kf[d * 33 + 16 + y];
        ar += qr * kr - qi * ki;
        ai += qr * ki + qi * kr;
    }
    float re, im;
    float a2 = 2.f * ar, b2 = 2.f * ai;
    if (fabsf(a2) < 80.f) {
        float den = coshf(a2) + cosf(b2);
        re = sinhf(a2) / den;
        im = sinf(b2) / den;
    } else {
        re = copysignf(1.f, ar);
        im = 0.f;
    }
    qkr[x * 17 + y] = re;
    qki[x * 17 + y] = im;
    __syncthreads();

    int xx = tid & 15, db = tid >> 4;
    #pragma unroll
    for (int i = 0; i < 4; i++) {
        int d = db + i * 16;
        float cr = 0.f, ci = 0.f;
        #pragma unroll
        for (int yy = 0; yy < 16; yy++) {
            float tr = qkr[xx * 17 + yy], ti = qki[xx * 17 + yy];
            float vr = vf[d * 33 + yy],   vi = vf[d * 33 + 16 + yy];
            cr += tr * vr - ti * vi;
            ci += tr * vi + ti * vr;
        }
        G[((size_t)b * 32 + xx) * DH + d * 64 + h]      = cr;
        G[((size_t)b * 32 + 16 + xx) * DH + d * 64 + h] = ci;
    }
}

// ---------------- stage C: inverse, radix-2 Hermitian over t ----------------
// NOTE: no min-waves launch_bounds here either — gr/gi is 64 floats/thread.
__global__ __launch_bounds__(256) void stageC(const float* __restrict__ G,
                                              const float* __restrict__ Bt2,
                                              float* __restrict__ out) {
    __shared__ float w[TT * 32];   // 2 KB basis tile
    int tid = threadIdx.x;
    int c   = blockIdx.y;          // t-tile over [0,1024), 64 tiles
    int b   = blockIdx.z;

    #pragma unroll
    for (int it = 0; it < TT * 32 / 256; it++)
        w[it * 256 + tid] = Bt2[c * (TT * 32) + it * 256 + tid];
    __syncthreads();

    int dh2 = blockIdx.x * 256 + tid;
    float2 gr[16], gi[16];
    const float2* gp = (const float2*)G + (size_t)b * 32 * DH2 + dh2;
    #pragma unroll
    for (int m = 0; m < 16; m++) {
        gr[m] = gp[(size_t)m * DH2];
        gi[m] = gp[(size_t)(16 + m) * DH2];
    }

    float2* o0 = (float2*)out + ((size_t)b * T_DIM + (size_t)c * TT) * DH2 + dh2;
    #pragma unroll 2
    for (int tl = 0; tl < TT; tl++) {
        const float* ww = &w[tl * 32];
        float2 E = make_float2(0.f, 0.f), O = make_float2(0.f, 0.f);
        #pragma unroll
        for (int m = 0; m < 16; m += 2) {
            E.x = fmaf(ww[2 * m],     gr[m].x, E.x);
            E.x = fmaf(ww[2 * m + 1], gi[m].x, E.x);
            E.y = fmaf(ww[2 * m],     gr[m].y, E.y);
            E.y = fmaf(ww[2 * m + 1], gi[m].y, E.y);
        }
        #pragma unroll
        for (int m = 1; m < 16; m += 2) {
            O.x = fmaf(ww[2 * m],     gr[m].x, O.x);
            O.x = fmaf(ww[2 * m + 1], gi[m].x, O.x);
            O.y = fmaf(ww[2 * m],     gr[m].y, O.y);
            O.y = fmaf(ww[2 * m + 1], gi[m].y, O.y);
        }
        o0[(size_t)tl * DH2] = make_float2(E.x + O.x, E.y + O.y);
        o0[(size_t)(tl + 1024) * DH2] = make_float2(E.x - O.x, E.y - O.y);
    }
}

extern "C" void kernel_launch(void* const* d_in, const int* in_sizes, int n_in,
                              void* d_out, int out_size, void* d_ws, size_t ws_size,
                              hipStream_t stream) {
    const float* q = (const float*)d_in[0];
    const float* k = (const float*)d_in[1];
    const float* v = (const float*)d_in[2];
    float* out = (float*)d_out;

    char* ws = (char*)d_ws;
    float* WA  = (float*)ws;                         //    65536 B
    float* Bt2 = (float*)(ws + 65536);               //   131072 B
    const size_t base = 65536 + 131072;

    const size_t psz16 = (size_t)12 * 16 * 32 * DH * 4;   // 100663296 B
    const size_t psz8  = (size_t)12 *  8 * 32 * DH * 4;   //  50331648 B
    const size_t ysz   = 6291456, gsz = 2097152;
    const bool big = ws_size >= base + psz16 + ysz + gsz; // 109.2 MB

    size_t psz = big ? psz16 : psz8;
    float* P = (float*)(ws + base);
    float* Y = (float*)(ws + base + psz);
    float* G = (float*)(ws + base + psz + ysz);

    init_tables<<<192, 256, 0, stream>>>(WA, Bt2);
    if (big) {
        stageA<16><<<dim3(8, 16, 12), 256, 0, stream>>>(q, k, v, WA, P);
        reduceP<16><<<1536, 256, 0, stream>>>((const float4*)P, (float4*)Y);
    } else {
        stageA<8><<<dim3(8, 8, 12), 256, 0, stream>>>(q, k, v, WA, P);
        reduceP<8><<<1536, 256, 0, stream>>>((const float4*)P, (float4*)Y);
    }
    stageB<<<256, 256, 0, stream>>>(Y, G);
    stageC<<<dim3(8, 64, 4), 256, 0, stream>>>(G, Bt2, out);
}

// Round 4
// 435.392 us; speedup vs baseline: 2.9635x; 1.0724x over previous
//
#include <hip/hip_runtime.h>
#include <hip/hip_bf16.h>
#include <math.h>

// FEAf lowpass: b=4, t=2048, c=64, mw=64, modes=16, SCALE=1/4096.
// Stage A v3: LDS-staged radix-4 DFT. 4 waves/block cooperatively stage+fold
//   a (NT=4 t'-steps x 4 quarters x 256 dh) tile; fold done ONCE at staging;
//   each thread then accumulates all 16 modes for ONE dh float (32 acc regs,
//   was 64 -> VGPR ceiling gone). Double-buffered LDS (32 KB), issue-early /
//   fold-late staging hides HBM latency under the FMA phase.
//   Twiddles read at wave-uniform addresses from WA -> scalarized s_loads.
// reduceP: sum chunk partials (CH=8, 50 MB of P traffic).
// Stage B: per (b,h) complex 16x16 attention w/ complex tanh.
// Stage C: 16-mode inverse (radix-2 Hermitian over t), TT=16.
// (Round-3 resubmit: prior bench was an infra failure, not a kernel failure.)

#define T_DIM 2048
#define DH 4096           // c*mw
#define DH2 2048          // float2 view
#define CH 8              // stageA chunks over t' in [0,512)
#define TPCH 64           // t' per chunk
#define NT 4              // t'-steps per phase (= waves per block)
#define NPH (TPCH / NT)   // 16 phases
#define TT 16             // stageC t-tile

__device__ inline float4 f4add(float4 a, float4 b) {
    return make_float4(a.x + b.x, a.y + b.y, a.z + b.z, a.w + b.w);
}
__device__ inline float4 f4sub(float4 a, float4 b) {
    return make_float4(a.x - b.x, a.y - b.y, a.z - b.z, a.w - b.w);
}

// ---------------- twiddle tables ----------------
// WA[t'][2m]=cos(2pi m t'/2048), WA[t'][2m+1]=sin(...)           (t' in [0,512))
// Bt2[t][2m]=coef_m cos(2pi m t/2048), [2m+1]=-coef_m sin(...)   (t in [0,1024))
__global__ void init_tables(float* __restrict__ WA, float* __restrict__ Bt2) {
    int i = blockIdx.x * 256 + threadIdx.x;
    const float TWO_PI = 6.2831853071795864769f;
    if (i < 512 * 32) {
        int t = i >> 5, r = i & 31, m = r >> 1;
        int ph = (m * t) & 2047;
        float ang = TWO_PI * (float)ph * (1.0f / 2048.0f);
        WA[i] = (r & 1) ? sinf(ang) : cosf(ang);
    }
    int i2 = i - 512 * 32;
    if (i2 >= 0 && i2 < 1024 * 32) {
        int t = i2 >> 5, r = i2 & 31, m = r >> 1;
        int ph = (m * t) & 2047;
        float ang = TWO_PI * (float)ph * (1.0f / 2048.0f);
        const float S2 = 1.0f / (4096.0f * 2048.0f);
        float coef = (m == 0 ? 1.0f : 2.0f) * S2;
        float val;
        if (!(r & 1)) val = coef * cosf(ang);
        else          val = (m == 0) ? 0.0f : -coef * sinf(ang);
        Bt2[i2] = val;
    }
}

// ---------------- stage A ----------------
// P[tz][chunk][j][dh]; j: 0..15 Re, 16..31 Im. tz = tensor*4 + b.
__global__ __launch_bounds__(256) void stageA(
        const float* __restrict__ q, const float* __restrict__ k,
        const float* __restrict__ v, const float* __restrict__ WA,
        float* __restrict__ P) {
    // elds[buf][t-step][array e/f/d0/d1][dh slot]
    __shared__ float elds[2][NT][4][256];

    int tid  = threadIdx.x;
    int bx   = blockIdx.x;        // dh tile [0,16), 256 floats each
    int c    = blockIdx.y;        // chunk [0,CH)
    int tz   = blockIdx.z;
    int tensor = tz >> 2, b = tz & 3;
    int iw   = tid >> 6;          // wave id = staged t-step
    int lane = tid & 63;

    const float* srcf = (tensor == 0 ? q : tensor == 1 ? k : v)
                        + (size_t)b * T_DIM * DH;
    const float4* src4 = (const float4*)srcf;   // 1024 float4 per t-row
    int f4base = bx * 64 + lane;                // float4 index within row

    float accR[16], accI[16];
    #pragma unroll
    for (int m = 0; m < 16; m++) { accR[m] = 0.f; accI[m] = 0.f; }

    // ---- prologue: stage phase 0 into buf 0 ----
    {
        int t0 = c * TPCH + iw;
        float4 x0 = src4[(size_t)t0 * 1024 + f4base];
        float4 x1 = src4[(size_t)(t0 + 512) * 1024 + f4base];
        float4 x2 = src4[(size_t)(t0 + 1024) * 1024 + f4base];
        float4 x3 = src4[(size_t)(t0 + 1536) * 1024 + f4base];
        float4 u0 = f4add(x0, x2), u1 = f4add(x1, x3);
        float4 dd0 = f4sub(x0, x2), dd1 = f4sub(x1, x3);
        ((float4*)&elds[0][iw][0][0])[lane] = f4add(u0, u1);   // e
        ((float4*)&elds[0][iw][1][0])[lane] = f4sub(u0, u1);   // f
        ((float4*)&elds[0][iw][2][0])[lane] = dd0;
        ((float4*)&elds[0][iw][3][0])[lane] = dd1;
    }
    __syncthreads();

    // ---- main loop: compute phase ph from buf ph&1; stage ph+1 into buf^1 ----
    for (int ph = 0; ph < NPH; ph++) {
        float4 n0, n1, n2, n3;
        const bool has_next = (ph < NPH - 1);
        if (has_next) {   // issue next tile's loads EARLY (overlap with FMAs)
            int t0 = c * TPCH + (ph + 1) * NT + iw;
            n0 = src4[(size_t)t0 * 1024 + f4base];
            n1 = src4[(size_t)(t0 + 512) * 1024 + f4base];
            n2 = src4[(size_t)(t0 + 1024) * 1024 + f4base];
            n3 = src4[(size_t)(t0 + 1536) * 1024 + f4base];
        }
        // compute: this thread owns dh float (bx*256 + tid), all 16 modes
        int bsel = ph & 1;
        #pragma unroll
        for (int i = 0; i < NT; i++) {
            float ee  = elds[bsel][i][0][tid];
            float ff  = elds[bsel][i][1][tid];
            float dd0 = elds[bsel][i][2][tid];
            float dd1 = elds[bsel][i][3][tid];
            const float* tw = WA + (size_t)(c * TPCH + ph * NT + i) * 32;
            #pragma unroll
            for (int m = 0; m < 16; m++) {
                float cm = tw[2 * m], sm = tw[2 * m + 1];
                if ((m & 3) == 0) {
                    accR[m] = fmaf(cm, ee, accR[m]);
                    accI[m] = fmaf(-sm, ee, accI[m]);
                } else if ((m & 3) == 2) {
                    accR[m] = fmaf(cm, ff, accR[m]);
                    accI[m] = fmaf(-sm, ff, accI[m]);
                } else if ((m & 3) == 1) {
                    accR[m] = fmaf(cm, dd0, fmaf(-sm, dd1, accR[m]));
                    accI[m] = fmaf(-sm, dd0, fmaf(-cm, dd1, accI[m]));
                } else {
                    accR[m] = fmaf(cm, dd0, fmaf(sm, dd1, accR[m]));
                    accI[m] = fmaf(-sm, dd0, fmaf(cm, dd1, accI[m]));
                }
            }
        }
        if (has_next) {   // fold + write into the other buffer, then barrier
            int nb = (ph + 1) & 1;
            float4 u0 = f4add(n0, n2), u1 = f4add(n1, n3);
            float4 dd0 = f4sub(n0, n2), dd1 = f4sub(n1, n3);
            ((float4*)&elds[nb][iw][0][0])[lane] = f4add(u0, u1);
            ((float4*)&elds[nb][iw][1][0])[lane] = f4sub(u0, u1);
            ((float4*)&elds[nb][iw][2][0])[lane] = dd0;
            ((float4*)&elds[nb][iw][3][0])[lane] = dd1;
            __syncthreads();
        }
    }

    // ---- store partials: this thread's dh float for all 32 j ----
    float* pp = P + ((size_t)(tz * CH + c) * 32) * DH + bx * 256 + tid;
    #pragma unroll
    for (int m = 0; m < 16; m++) {
        pp[(size_t)m * DH]        = accR[m];
        pp[(size_t)(16 + m) * DH] = accI[m];
    }
}

// ---------------- reduce chunk partials: Y[tz][j][dh] ----------------
__global__ __launch_bounds__(256) void reduceP(const float4* __restrict__ P,
                                               float4* __restrict__ Y) {
    size_t i   = (size_t)blockIdx.x * 256 + threadIdx.x;  // 12*32*1024
    size_t tzj = i >> 10;
    size_t dh4 = i & 1023;
    size_t tz  = tzj >> 5;
    size_t j   = tzj & 31;
    const float4* p = P + ((tz * CH) * 32 + j) * 1024 + dh4;
    float4 s = make_float4(0.f, 0.f, 0.f, 0.f);
    #pragma unroll
    for (int cc = 0; cc < CH; cc++) {
        float4 t = p[(size_t)cc * 32 * 1024];
        s.x += t.x; s.y += t.y; s.z += t.z; s.w += t.w;
    }
    Y[i] = s;
}

// ---------------- stage B: complex mode-space attention ----------------
// G[b][j][dh], j: 0..15 Re(qkv), 16..31 Im(qkv)
__global__ __launch_bounds__(256) void stageB(const float* __restrict__ Y,
                                              float* __restrict__ G) {
    __shared__ float qf[64 * 33];
    __shared__ float kf[64 * 33];
    __shared__ float vf[64 * 33];
    __shared__ float qkr[16 * 17];
    __shared__ float qki[16 * 17];

    int tid = threadIdx.x;
    int bh  = blockIdx.x;
    int b   = bh >> 6;
    int h   = bh & 63;

    #pragma unroll
    for (int tensor = 0; tensor < 3; tensor++) {
        float* dst = (tensor == 0 ? qf : tensor == 1 ? kf : vf);
        const float* yp = Y + ((size_t)(tensor * 4 + b) * 32) * DH + h;
        #pragma unroll
        for (int it = 0; it < 8; it++) {
            int p = it * 256 + tid;
            int d = p & 63, j = p >> 6;
            dst[d * 33 + j] = yp[(size_t)j * DH + d * 64];
        }
    }
    __syncthreads();

    int x = tid >> 4, y = tid & 15;
    float ar = 0.f, ai = 0.f;
    #pragma unroll 4
    for (int d = 0; d < 64; d++) {
        float qr = qf[d * 33 + x],      qi = qf[d * 33 + 16 + x];
        float kr = kf[d * 33 + y],      ki = kf[d * 33 + 16 + y];
        ar += qr * kr - qi * ki;
        ai += qr * ki + qi * kr;
    }
    float re, im;
    float a2 = 2.f * ar, b2 = 2.f * ai;
    if (fabsf(a2) < 80.f) {
        float den = coshf(a2) + cosf(b2);
        re = sinhf(a2) / den;
        im = sinf(b2) / den;
    } else {
        re = copysignf(1.f, ar);
        im = 0.f;
    }
    qkr[x * 17 + y] = re;
    qki[x * 17 + y] = im;
    __syncthreads();

    int xx = tid & 15, db = tid >> 4;
    #pragma unroll
    for (int i = 0; i < 4; i++) {
        int d = db + i * 16;
        float cr = 0.f, ci = 0.f;
        #pragma unroll
        for (int yy = 0; yy < 16; yy++) {
            float tr = qkr[xx * 17 + yy], ti = qki[xx * 17 + yy];
            float vr = vf[d * 33 + yy],   vi = vf[d * 33 + 16 + yy];
            cr += tr * vr - ti * vi;
            ci += tr * vi + ti * vr;
        }
        G[((size_t)b * 32 + xx) * DH + d * 64 + h]      = cr;
        G[((size_t)b * 32 + 16 + xx) * DH + d * 64 + h] = ci;
    }
}

// ---------------- stage C: inverse, radix-2 Hermitian over t ----------------
// NOTE: no min-waves launch_bounds — gr/gi is 64 floats/thread (round-1 spill).
__global__ __launch_bounds__(256) void stageC(const float* __restrict__ G,
                                              const float* __restrict__ Bt2,
                                              float* __restrict__ out) {
    __shared__ float w[TT * 32];   // 2 KB basis tile
    int tid = threadIdx.x;
    int c   = blockIdx.y;          // t-tile over [0,1024), 64 tiles
    int b   = blockIdx.z;

    #pragma unroll
    for (int it = 0; it < TT * 32 / 256; it++)
        w[it * 256 + tid] = Bt2[c * (TT * 32) + it * 256 + tid];
    __syncthreads();

    int dh2 = blockIdx.x * 256 + tid;
    float2 gr[16], gi[16];
    const float2* gp = (const float2*)G + (size_t)b * 32 * DH2 + dh2;
    #pragma unroll
    for (int m = 0; m < 16; m++) {
        gr[m] = gp[(size_t)m * DH2];
        gi[m] = gp[(size_t)(16 + m) * DH2];
    }

    float2* o0 = (float2*)out + ((size_t)b * T_DIM + (size_t)c * TT) * DH2 + dh2;
    #pragma unroll 2
    for (int tl = 0; tl < TT; tl++) {
        const float* ww = &w[tl * 32];
        float2 E = make_float2(0.f, 0.f), O = make_float2(0.f, 0.f);
        #pragma unroll
        for (int m = 0; m < 16; m += 2) {
            E.x = fmaf(ww[2 * m],     gr[m].x, E.x);
            E.x = fmaf(ww[2 * m + 1], gi[m].x, E.x);
            E.y = fmaf(ww[2 * m],     gr[m].y, E.y);
            E.y = fmaf(ww[2 * m + 1], gi[m].y, E.y);
        }
        #pragma unroll
        for (int m = 1; m < 16; m += 2) {
            O.x = fmaf(ww[2 * m],     gr[m].x, O.x);
            O.x = fmaf(ww[2 * m + 1], gi[m].x, O.x);
            O.y = fmaf(ww[2 * m],     gr[m].y, O.y);
            O.y = fmaf(ww[2 * m + 1], gi[m].y, O.y);
        }
        o0[(size_t)tl * DH2] = make_float2(E.x + O.x, E.y + O.y);
        o0[(size_t)(tl + 1024) * DH2] = make_float2(E.x - O.x, E.y - O.y);
    }
}

extern "C" void kernel_launch(void* const* d_in, const int* in_sizes, int n_in,
                              void* d_out, int out_size, void* d_ws, size_t ws_size,
                              hipStream_t stream) {
    const float* q = (const float*)d_in[0];
    const float* k = (const float*)d_in[1];
    const float* v = (const float*)d_in[2];
    float* out = (float*)d_out;

    char* ws = (char*)d_ws;
    float* WA  = (float*)ws;                         //    65536 B
    float* Bt2 = (float*)(ws + 65536);               //   131072 B
    const size_t base = 65536 + 131072;

    const size_t psz = (size_t)12 * CH * 32 * DH * 4;   // 50331648 B
    const size_t ysz = 6291456;
    float* P = (float*)(ws + base);
    float* Y = (float*)(ws + base + psz);
    float* G = (float*)(ws + base + psz + ysz);

    init_tables<<<192, 256, 0, stream>>>(WA, Bt2);
    stageA<<<dim3(16, CH, 12), 256, 0, stream>>>(q, k, v, WA, P);
    reduceP<<<1536, 256, 0, stream>>>((const float4*)P, (float4*)Y);
    stageB<<<256, 256, 0, stream>>>(Y, G);
    stageC<<<dim3(8, 64, 4), 256, 0, stream>>>(G, Bt2, out);
}